// Round 2
// baseline (23517.014 us; speedup 1.0000x reference)
//
#include <hip/hip_runtime.h>
#include <math.h>

// ---------------------------------------------------------------------------
// VQ-VAE forward, fp32, NHWC intermediates, quad-decomposed transposed convs.
//  x (1024,1,50,50) NCHW (C=1 == pixel-contig)
//  conv1 k3s2p1+relu -> h1 (n,25,25,32) NHWC      [region B]
//  conv2 k3s2p1+relu -> h2 (n,13,13,64) NHWC      [region A]
//  conv3 1x1         -> z  (n,13,13,64) NHWC      [region B]
//  VQ (512x64)       -> q  (n,13,13,64) NHWC      [region A]  + loss atomic
//  tconv1 13->25+relu-> d1 (n,25,25,64) NHWC      [region B]
//  tconv2 25->50+relu-> d2 (n,50,50,32) NHWC      [region A]
//  convf k3s1p1+sigm -> out (n,50,50)
// ws layout (floats): tw2[18432] tw3[4096] twd1[36864] twd2[18432] cn[512]
//                     then regA (80000/img) regB (40000/img)
// ---------------------------------------------------------------------------

__global__ __launch_bounds__(64) void k_zero(float* __restrict__ p) {
    if (threadIdx.x == 0 && blockIdx.x == 0) *p = 0.f;
}

// ---- weight transpose preps (run once per call) ----------------------------
// tw2: [cog4][tap9][cc8][col16][j4] <- ew2[co=cog*16+col][ci=cc*4+j][tap]
__global__ __launch_bounds__(256) void k_prep_tw2(const float* __restrict__ w,
                                                  float* __restrict__ o) {
    int i = blockIdx.x * 256 + threadIdx.x;  // 18432
    int j = i & 3, col = (i >> 2) & 15, cc = (i >> 6) & 7, tap = (i >> 9) % 9, cog = i / 4608;
    int co = cog * 16 + col, ci = cc * 4 + j;
    o[i] = w[(co * 32 + ci) * 9 + tap];
}
// tw3: [cg4][ci64][c16] <- ew3[c_global=cg*16+c][ci]
__global__ __launch_bounds__(256) void k_prep_tw3(const float* __restrict__ w,
                                                  float* __restrict__ o) {
    int i = blockIdx.x * 256 + threadIdx.x;  // 4096
    int c = i & 15, ci = (i >> 4) & 63, cg = i >> 10;
    o[i] = w[(cg * 16 + c) * 64 + ci];
}
// twd1: [cog4][cc16][tap9][col16][j4] <- dw1[co=cog*16+col][ci=cc*4+j][tap]
__global__ __launch_bounds__(256) void k_prep_twd1(const float* __restrict__ w,
                                                   float* __restrict__ o) {
    int i = blockIdx.x * 256 + threadIdx.x;  // 36864
    int j = i & 3, col = (i >> 2) & 15, tap = (i >> 6) % 9, cc = (i / 576) & 15, cog = i / 9216;
    int co = cog * 16 + col, ci = cc * 4 + j;
    o[i] = w[(co * 64 + ci) * 9 + tap];
}
// twd2: [cog2][cc16][tap9][col16][j4] <- dw2[co=cog*16+col][ci=cc*4+j][tap]
__global__ __launch_bounds__(256) void k_prep_twd2(const float* __restrict__ w,
                                                   float* __restrict__ o) {
    int i = blockIdx.x * 256 + threadIdx.x;  // 18432
    int j = i & 3, col = (i >> 2) & 15, tap = (i >> 6) % 9, cc = (i / 576) & 15, cog = i / 9216;
    int co = cog * 16 + col, ci = cc * 4 + j;
    o[i] = w[(co * 64 + ci) * 9 + tap];
}
// cn[k] = ||cb[k]||^2
__global__ __launch_bounds__(256) void k_prep_cn(const float* __restrict__ cb,
                                                 float* __restrict__ cn) {
    int k = blockIdx.x * 256 + threadIdx.x;  // 512
    const float* r = cb + k * 64;
    float s = 0.f;
#pragma unroll
    for (int c = 0; c < 64; ++c) s += r[c] * r[c];
    cn[k] = s;
}

// ---- conv1: x (bc,50,50) -> h1 (bc,25,25,32) NHWC, relu --------------------
__global__ __launch_bounds__(256) void k_conv1(const float* __restrict__ x,
                                               const float* __restrict__ w,   // ew1 OIHW
                                               const float* __restrict__ b,
                                               float* __restrict__ h1, int total) {
    __shared__ float4 wl4[72];  // [tap9][co32] as f4
    float* wl = (float*)wl4;
    int tid = threadIdx.x;
    for (int t = tid; t < 288; t += 256) {
        int tap = t >> 5, co = t & 31;
        wl[t] = w[co * 9 + tap];
    }
    __syncthreads();
    int pix = blockIdx.x * 256 + tid;
    if (pix >= total) return;
    int n = pix / 625, p = pix % 625, oh = p / 25, ow = p % 25;
    const float* xp = x + (size_t)n * 2500;
    float4 a[8];
#pragma unroll
    for (int j = 0; j < 8; ++j) a[j] = ((const float4*)b)[j];
#pragma unroll
    for (int kh = 0; kh < 3; ++kh) {
        int ih = 2 * oh - 1 + kh;
        if ((unsigned)ih >= 50u) continue;
#pragma unroll
        for (int kw = 0; kw < 3; ++kw) {
            int iw = 2 * ow - 1 + kw;
            if ((unsigned)iw >= 50u) continue;
            float v = xp[ih * 50 + iw];
            int tap = kh * 3 + kw;
#pragma unroll
            for (int j = 0; j < 8; ++j) {
                float4 ww = wl4[tap * 8 + j];
                a[j].x += v * ww.x; a[j].y += v * ww.y;
                a[j].z += v * ww.z; a[j].w += v * ww.w;
            }
        }
    }
    float4* op = (float4*)(h1 + (size_t)pix * 32);
#pragma unroll
    for (int j = 0; j < 8; ++j) {
        float4 r;
        r.x = fmaxf(a[j].x, 0.f); r.y = fmaxf(a[j].y, 0.f);
        r.z = fmaxf(a[j].z, 0.f); r.w = fmaxf(a[j].w, 0.f);
        op[j] = r;
    }
}

// ---- conv2: h1 (bc,25,25,32) -> h2 (bc,13,13,64) NHWC, relu ----------------
// block: 16 pix x 16 col; grid (ceil(bc*169/16), 4 cog)
__global__ __launch_bounds__(256) void k_conv2(const float* __restrict__ h1,
                                               const float* __restrict__ tw2,
                                               const float* __restrict__ b,
                                               float* __restrict__ h2, int npix) {
    __shared__ float4 wl4[1152];  // [tap9][cc8][col16] f4-over-ci
    int tid = threadIdx.x;
    const float4* src = (const float4*)(tw2 + (size_t)blockIdx.y * 4608);
    for (int t = tid; t < 1152; t += 256) wl4[t] = src[t];
    __syncthreads();
    int col = tid & 15, pl = tid >> 4;
    int pix = blockIdx.x * 16 + pl;
    if (pix >= npix) return;
    int n = pix / 169, p = pix % 169, oh = p / 13, ow = p % 13;
    int co = blockIdx.y * 16 + col;
    float acc = b[co];
#pragma unroll
    for (int kh = 0; kh < 3; ++kh) {
        int ih = 2 * oh - 1 + kh;
        if ((unsigned)ih >= 25u) continue;
#pragma unroll
        for (int kw = 0; kw < 3; ++kw) {
            int iw = 2 * ow - 1 + kw;
            if ((unsigned)iw >= 25u) continue;
            int tap = kh * 3 + kw;
            const float4* ip = (const float4*)(h1 + (((size_t)n * 25 + ih) * 25 + iw) * 32);
#pragma unroll
            for (int cc = 0; cc < 8; ++cc) {
                float4 v = ip[cc];
                float4 ww = wl4[(tap * 8 + cc) * 16 + col];
                acc += v.x * ww.x + v.y * ww.y + v.z * ww.z + v.w * ww.w;
            }
        }
    }
    h2[(size_t)pix * 64 + co] = fmaxf(acc, 0.f);
}

// ---- conv3 1x1: h2 (bc,13,13,64) -> z (bc,13,13,64) NHWC -------------------
// block 256 pix; grid (ceil(npix/256), 4 cg)
__global__ __launch_bounds__(256) void k_conv3(const float* __restrict__ h2,
                                               const float* __restrict__ tw3,
                                               const float* __restrict__ b,
                                               float* __restrict__ z, int npix) {
    __shared__ float4 wl4[1024];  // [ci64][c16] f4-over-c
    int tid = threadIdx.x;
    int cg = blockIdx.y;
    const float4* src = (const float4*)(tw3 + (size_t)cg * 4096);
    for (int t = tid; t < 1024; t += 256) wl4[t] = src[t];
    __syncthreads();
    int pix = blockIdx.x * 256 + tid;
    if (pix >= npix) return;
    float4 a[4];
#pragma unroll
    for (int c4 = 0; c4 < 4; ++c4) a[c4] = ((const float4*)b)[cg * 4 + c4];
    const float4* zp = (const float4*)(h2 + (size_t)pix * 64);
#pragma unroll
    for (int cc = 0; cc < 16; ++cc) {
        float4 v = zp[cc];
#pragma unroll
        for (int j = 0; j < 4; ++j) {
            float vj = (j == 0) ? v.x : (j == 1) ? v.y : (j == 2) ? v.z : v.w;
            int ci = cc * 4 + j;
#pragma unroll
            for (int c4 = 0; c4 < 4; ++c4) {
                float4 ww = wl4[ci * 4 + c4];
                a[c4].x += vj * ww.x; a[c4].y += vj * ww.y;
                a[c4].z += vj * ww.z; a[c4].w += vj * ww.w;
            }
        }
    }
    float4* op = (float4*)(z + (size_t)pix * 64 + cg * 16);
#pragma unroll
    for (int c4 = 0; c4 < 4; ++c4) op[c4] = a[c4];
}

// ---- VQ: z (bc,13,13,64) -> q (bc,13,13,64) NHWC + loss --------------------
__global__ __launch_bounds__(256) void k_vq(const float* __restrict__ z,
                                            const float* __restrict__ cb,
                                            const float* __restrict__ cn,
                                            float* __restrict__ q,
                                            float* __restrict__ loss, int npix) {
    __shared__ float4 cbl[2048];  // 128 codes x 16 f4 = 32KB
    __shared__ float red[4];
    int tid = threadIdx.x;
    int pix = blockIdx.x * 256 + tid;
    bool active = pix < npix;
    float4 z4[16];
    if (active) {
        const float4* zp = (const float4*)(z + (size_t)pix * 64);
#pragma unroll
        for (int i = 0; i < 16; ++i) z4[i] = zp[i];
    }
    float best = 3.4e38f;
    int bk = 0;
    const float4* cb4 = (const float4*)cb;
    for (int ch = 0; ch < 4; ++ch) {
        __syncthreads();
        for (int t = tid; t < 2048; t += 256) cbl[t] = cb4[ch * 2048 + t];
        __syncthreads();
        if (active) {
            for (int kl = 0; kl < 128; ++kl) {
                const float4* cr = cbl + kl * 16;
                float s0 = 0.f, s1 = 0.f;
#pragma unroll
                for (int i = 0; i < 16; i += 2) {
                    float4 a = z4[i], b0 = cr[i];
                    float4 c = z4[i + 1], d = cr[i + 1];
                    s0 += a.x * b0.x + a.y * b0.y + a.z * b0.z + a.w * b0.w;
                    s1 += c.x * d.x + c.y * d.y + c.z * d.z + c.w * d.w;
                }
                int k = ch * 128 + kl;
                float dd = cn[k] - 2.f * (s0 + s1);
                if (dd < best) { best = dd; bk = k; }
            }
        }
    }
    float lsum = 0.f;
    if (active) {
        float4* qp = (float4*)(q + (size_t)pix * 64);
#pragma unroll
        for (int i = 0; i < 16; ++i) {
            float4 cq = cb4[bk * 16 + i];
            float4 zz = z4[i];
            float dx = cq.x - zz.x, dy = cq.y - zz.y, dz = cq.z - zz.z, dw = cq.w - zz.w;
            lsum += dx * dx + dy * dy + dz * dz + dw * dw;
            qp[i] = cq;
        }
    }
#pragma unroll
    for (int off = 32; off > 0; off >>= 1) lsum += __shfl_down(lsum, off);
    if ((tid & 63) == 0) red[tid >> 6] = lsum;
    __syncthreads();
    if (tid == 0) {
        float t = red[0] + red[1] + red[2] + red[3];
        atomicAdd(loss, t * (1.25f / 11075584.f));  // /(1024*64*13*13)
    }
}

// ---- tconv1: q (bc,13,13,64) -> d1 (bc,25,25,64) NHWC, relu ----------------
// quad decomposition: thread = (quad m,mw in 13x13, col); block 16 quad x 16 col
// grid (ceil(bc*169/16), 4 cog)
__global__ __launch_bounds__(256) void k_tconv1(const float* __restrict__ in,
                                                const float* __restrict__ twd1,
                                                const float* __restrict__ b,
                                                float* __restrict__ out, int nquad) {
    __shared__ float4 wl4[2304];  // [cc16][tap9][col16] f4-over-ci
    int tid = threadIdx.x;
    const float4* src = (const float4*)(twd1 + (size_t)blockIdx.y * 9216);
    for (int t = tid; t < 2304; t += 256) wl4[t] = src[t];
    __syncthreads();
    int col = tid & 15, ql = tid >> 4;
    int quad = blockIdx.x * 16 + ql;
    if (quad >= nquad) return;
    int n = quad / 169, r = quad % 169, m = r / 13, mw = r % 13;
    int co = blockIdx.y * 16 + col;
    bool bm = (m + 1 < 13), bw = (mw + 1 < 13);
    const float* base = in + (((size_t)n * 13 + m) * 13 + mw) * 64;
    float acc0 = b[co], acc1 = acc0, acc2 = acc0, acc3 = acc0;
    const float4 zero = {0.f, 0.f, 0.f, 0.f};
    for (int cc = 0; cc < 16; ++cc) {
        float4 v00 = *(const float4*)(base + cc * 4);
        float4 v01 = bw ? *(const float4*)(base + 64 + cc * 4) : zero;
        float4 v10 = bm ? *(const float4*)(base + 13 * 64 + cc * 4) : zero;
        float4 v11 = (bm && bw) ? *(const float4*)(base + 14 * 64 + cc * 4) : zero;
#pragma unroll
        for (int jh = 0; jh < 3; ++jh) {
#pragma unroll
            for (int jw = 0; jw < 3; ++jw) {
                int tap = jh * 3 + jw;
                float4 v = (jh == 0) ? ((jw == 0) ? v11 : v10)
                                     : ((jw == 0) ? v01 : v00);
                float4 ww = wl4[(cc * 9 + tap) * 16 + col];
                float f = v.x * ww.x + v.y * ww.y + v.z * ww.z + v.w * ww.w;
                if (jh == 1 && jw == 1) acc0 += f;        // (even,even)
                else if (jh == 1) acc1 += f;              // (even,odd)
                else if (jw == 1) acc2 += f;              // (odd,even)
                else acc3 += f;                           // (odd,odd)
            }
        }
    }
    size_t ob = (((size_t)n * 25 + 2 * m) * 25 + 2 * mw) * 64 + co;
    out[ob] = fmaxf(acc0, 0.f);
    if (bw) out[ob + 64] = fmaxf(acc1, 0.f);
    if (bm) out[ob + 25 * 64] = fmaxf(acc2, 0.f);
    if (bm && bw) out[ob + 26 * 64] = fmaxf(acc3, 0.f);
}

// ---- tconv2: d1 (bc,25,25,64) -> d2 (bc,50,50,32) NHWC, relu ---------------
// grid (ceil(bc*625/16), 2 cog)
__global__ __launch_bounds__(256) void k_tconv2(const float* __restrict__ in,
                                                const float* __restrict__ twd2,
                                                const float* __restrict__ b,
                                                float* __restrict__ out, int nquad) {
    __shared__ float4 wl4[2304];
    int tid = threadIdx.x;
    const float4* src = (const float4*)(twd2 + (size_t)blockIdx.y * 9216);
    for (int t = tid; t < 2304; t += 256) wl4[t] = src[t];
    __syncthreads();
    int col = tid & 15, ql = tid >> 4;
    int quad = blockIdx.x * 16 + ql;
    if (quad >= nquad) return;
    int n = quad / 625, r = quad % 625, m = r / 25, mw = r % 25;
    int co = blockIdx.y * 16 + col;
    bool bm = (m + 1 < 25), bw = (mw + 1 < 25);
    const float* base = in + (((size_t)n * 25 + m) * 25 + mw) * 64;
    float acc0 = b[co], acc1 = acc0, acc2 = acc0, acc3 = acc0;
    const float4 zero = {0.f, 0.f, 0.f, 0.f};
    for (int cc = 0; cc < 16; ++cc) {
        float4 v00 = *(const float4*)(base + cc * 4);
        float4 v01 = bw ? *(const float4*)(base + 64 + cc * 4) : zero;
        float4 v10 = bm ? *(const float4*)(base + 25 * 64 + cc * 4) : zero;
        float4 v11 = (bm && bw) ? *(const float4*)(base + 26 * 64 + cc * 4) : zero;
#pragma unroll
        for (int jh = 0; jh < 3; ++jh) {
#pragma unroll
            for (int jw = 0; jw < 3; ++jw) {
                int tap = jh * 3 + jw;
                float4 v = (jh == 0) ? ((jw == 0) ? v11 : v10)
                                     : ((jw == 0) ? v01 : v00);
                float4 ww = wl4[(cc * 9 + tap) * 16 + col];
                float f = v.x * ww.x + v.y * ww.y + v.z * ww.z + v.w * ww.w;
                if (jh == 1 && jw == 1) acc0 += f;
                else if (jh == 1) acc1 += f;
                else if (jw == 1) acc2 += f;
                else acc3 += f;
            }
        }
    }
    size_t ob = (((size_t)n * 50 + 2 * m) * 50 + 2 * mw) * 32 + co;
    out[ob] = fmaxf(acc0, 0.f);
    out[ob + 32] = fmaxf(acc1, 0.f);
    out[ob + 50 * 32] = fmaxf(acc2, 0.f);
    out[ob + 51 * 32] = fmaxf(acc3, 0.f);
}

// ---- convf: d2 (bc,50,50,32) -> out (bc,50,50), sigmoid --------------------
__global__ __launch_bounds__(256) void k_convf(const float* __restrict__ in,
                                               const float* __restrict__ w,  // dw3 OIHW (1,32,3,3)
                                               const float* __restrict__ b,
                                               float* __restrict__ out, int total) {
    __shared__ float4 wl4[72];  // [tap9][ci32] f4
    float* wl = (float*)wl4;
    int tid = threadIdx.x;
    for (int t = tid; t < 288; t += 256) {
        int tap = t >> 5, ci = t & 31;
        wl[t] = w[ci * 9 + tap];
    }
    __syncthreads();
    int pix = blockIdx.x * 256 + tid;
    if (pix >= total) return;
    int n = pix / 2500, p = pix % 2500, oh = p / 50, ow = p % 50;
    float acc = b[0];
#pragma unroll
    for (int kh = 0; kh < 3; ++kh) {
        int ih = oh - 1 + kh;
        if ((unsigned)ih >= 50u) continue;
#pragma unroll
        for (int kw = 0; kw < 3; ++kw) {
            int iw = ow - 1 + kw;
            if ((unsigned)iw >= 50u) continue;
            int tap = kh * 3 + kw;
            const float4* ip = (const float4*)(in + (((size_t)n * 50 + ih) * 50 + iw) * 32);
#pragma unroll
            for (int cc = 0; cc < 8; ++cc) {
                float4 v = ip[cc];
                float4 ww = wl4[tap * 8 + cc];
                acc += v.x * ww.x + v.y * ww.y + v.z * ww.z + v.w * ww.w;
            }
        }
    }
    out[pix] = 1.f / (1.f + expf(-acc));
}

extern "C" void kernel_launch(void* const* d_in, const int* in_sizes, int n_in,
                              void* d_out, int out_size, void* d_ws, size_t ws_size,
                              hipStream_t stream) {
    const float* x   = (const float*)d_in[0];
    const float* ew1 = (const float*)d_in[1];
    const float* eb1 = (const float*)d_in[2];
    const float* ew2 = (const float*)d_in[3];
    const float* eb2 = (const float*)d_in[4];
    const float* ew3 = (const float*)d_in[5];
    const float* eb3 = (const float*)d_in[6];
    const float* cb  = (const float*)d_in[7];
    const float* dw1 = (const float*)d_in[8];
    const float* db1 = (const float*)d_in[9];
    const float* dw2 = (const float*)d_in[10];
    const float* db2 = (const float*)d_in[11];
    const float* dw3 = (const float*)d_in[12];
    const float* db3 = (const float*)d_in[13];
    float* out = (float*)d_out;
    float* loss = out + 2560000;

    float* ws  = (float*)d_ws;
    float* tw2  = ws;              // 18432
    float* tw3  = ws + 18432;      // 4096
    float* twd1 = ws + 22528;      // 36864
    float* twd2 = ws + 59392;      // 18432
    float* cn   = ws + 77824;      // 512
    const size_t tw_floats = 78336;

    const int B = 1024;
    const size_t A_per = 80000, B_per = 40000;  // floats per image
    size_t avail = (ws_size / 4 > tw_floats) ? ws_size / 4 - tw_floats : 0;
    int BC = (int)(avail / (A_per + B_per));
    if (BC > B) BC = B;
    if (BC < 1) BC = 1;
    float* regA = ws + tw_floats;
    float* regB = regA + (size_t)BC * A_per;

    // preps
    k_zero<<<1, 64, 0, stream>>>(loss);
    k_prep_tw2 <<<72, 256, 0, stream>>>(ew2, tw2);
    k_prep_tw3 <<<16, 256, 0, stream>>>(ew3, tw3);
    k_prep_twd1<<<144, 256, 0, stream>>>(dw1, twd1);
    k_prep_twd2<<<72, 256, 0, stream>>>(dw2, twd2);
    k_prep_cn  <<<2, 256, 0, stream>>>(cb, cn);

    for (int n0 = 0; n0 < B; n0 += BC) {
        int bc = (B - n0 < BC) ? (B - n0) : BC;
        const float* xch = x + (size_t)n0 * 2500;

        int t1 = bc * 625;   // conv1 pixels -> h1 in regB
        k_conv1<<<(t1 + 255) / 256, 256, 0, stream>>>(xch, ew1, eb1, regB, t1);

        int npix = bc * 169; // conv2: regB -> regA (h2)
        dim3 g2((npix + 15) / 16, 4);
        k_conv2<<<g2, 256, 0, stream>>>(regB, tw2, eb2, regA, npix);

        dim3 g3((npix + 255) / 256, 4);  // conv3: regA -> regB (z)
        k_conv3<<<g3, 256, 0, stream>>>(regA, tw3, eb3, regB, npix);

        // vq: regB (z) -> regA (q)
        k_vq<<<(npix + 255) / 256, 256, 0, stream>>>(regB, cb, cn, regA, loss, npix);

        dim3 g4((npix + 15) / 16, 4);  // tconv1: regA (q) -> regB (d1); nquad == npix
        k_tconv1<<<g4, 256, 0, stream>>>(regA, twd1, db1, regB, npix);

        int nq2 = bc * 625;  // tconv2: regB (d1) -> regA (d2)
        dim3 g5((nq2 + 15) / 16, 2);
        k_tconv2<<<g5, 256, 0, stream>>>(regB, twd2, db2, regA, nq2);

        int t6 = bc * 2500;  // convf: regA -> out
        k_convf<<<(t6 + 255) / 256, 256, 0, stream>>>(regA, dw3, db3, out + (size_t)n0 * 2500, t6);
    }
}

// Round 3
// 3284.196 us; speedup vs baseline: 7.1607x; 7.1607x over previous
//
#include <hip/hip_runtime.h>
#include <math.h>

// ---------------------------------------------------------------------------
// VQ-VAE forward, fp32, NHWC intermediates.
// Key idea: lane = spatial position, thread owns a co-group in registers;
// weights are read with wave-uniform indices -> s_load (scalar cache), so
// VALU does almost pure FMA. No LDS weight tiles, no spills (#pragma unroll 1
// on channel-chunk loops + __launch_bounds__(256,4)).
//  x (1024,1,50,50)
//  conv1 k3s2p1+relu -> h1 (n,25,25,32)   [regB]
//  conv2 k3s2p1+relu -> h2 (n,13,13,64)   [regA]
//  conv3 1x1         -> z  (n,13,13,64)   [regB]
//  VQ 512x64         -> q  (n,13,13,64)   [regA] + loss atomic
//  tconv1 13->25+relu-> d1 (n,25,25,64)   [regB]
//  tconv2 25->50+relu-> d2 (n,50,50,32)   [regA]
//  convf k3s1p1+sigm -> out (n,50,50)
// ---------------------------------------------------------------------------

__global__ __launch_bounds__(64) void k_zero(float* __restrict__ p) {
    if (threadIdx.x == 0 && blockIdx.x == 0) *p = 0.f;
}

// ---- weight transpose preps ------------------------------------------------
// w2t: [cog2][cc8][tap9][j4][co32] <- ew2[co_g=cog*32+co][ci=cc*4+j][tap]
__global__ __launch_bounds__(256) void k_prep_w2t(const float* __restrict__ w,
                                                  float* __restrict__ o) {
    int i = blockIdx.x * 256 + threadIdx.x;  // 18432
    int co = i & 31, j = (i >> 5) & 3, tap = (i >> 7) % 9;
    int q = (i >> 7) / 9, cc = q & 7, cog = q >> 3;
    o[i] = w[((cog * 32 + co) * 32 + cc * 4 + j) * 9 + tap];
}
// w3t: [ci64][co64] <- ew3[co][ci]
__global__ __launch_bounds__(256) void k_prep_w3t(const float* __restrict__ w,
                                                  float* __restrict__ o) {
    int i = blockIdx.x * 256 + threadIdx.x;  // 4096
    int co = i & 63, ci = i >> 6;
    o[i] = w[co * 64 + ci];
}
// wt1: [cog4][cc16][tap9][j4][co16] <- dw1[co_g=cog*16+co][ci=cc*4+j][tap]
__global__ __launch_bounds__(256) void k_prep_wt1(const float* __restrict__ w,
                                                  float* __restrict__ o) {
    int i = blockIdx.x * 256 + threadIdx.x;  // 36864
    int co = i & 15, j = (i >> 4) & 3, tap = (i >> 6) % 9;
    int q = (i >> 6) / 9, cc = q & 15, cog = q >> 4;
    o[i] = w[((cog * 16 + co) * 64 + cc * 4 + j) * 9 + tap];
}
// wt2: [cog2][cc16][tap9][j4][co16] <- dw2[co_g=cog*16+co][ci=cc*4+j][tap]
__global__ __launch_bounds__(256) void k_prep_wt2(const float* __restrict__ w,
                                                  float* __restrict__ o) {
    int i = blockIdx.x * 256 + threadIdx.x;  // 18432
    int co = i & 15, j = (i >> 4) & 3, tap = (i >> 6) % 9;
    int q = (i >> 6) / 9, cc = q & 15, cog = q >> 4;
    o[i] = w[((cog * 16 + co) * 64 + cc * 4 + j) * 9 + tap];
}
// cn[k] = ||cb[k]||^2
__global__ __launch_bounds__(256) void k_prep_cn(const float* __restrict__ cb,
                                                 float* __restrict__ cn) {
    int k = blockIdx.x * 256 + threadIdx.x;  // 512
    const float* r = cb + k * 64;
    float s = 0.f;
#pragma unroll
    for (int c = 0; c < 64; ++c) s += r[c] * r[c];
    cn[k] = s;
}

// ---- conv1: x (bc,50,50) -> h1 (bc,25,25,32), relu -------------------------
__global__ __launch_bounds__(256) void k_conv1(const float* __restrict__ x,
                                               const float* __restrict__ w,   // ew1 OIHW
                                               const float* __restrict__ b,
                                               float* __restrict__ h1, int total) {
    __shared__ float4 wl4[72];  // [tap9][co32] as f4
    float* wl = (float*)wl4;
    int tid = threadIdx.x;
    for (int t = tid; t < 288; t += 256) {
        int tap = t >> 5, co = t & 31;
        wl[t] = w[co * 9 + tap];
    }
    __syncthreads();
    int pix = blockIdx.x * 256 + tid;
    if (pix >= total) return;
    int n = pix / 625, p = pix % 625, oh = p / 25, ow = p % 25;
    const float* xp = x + (size_t)n * 2500;
    float4 a[8];
#pragma unroll
    for (int j = 0; j < 8; ++j) a[j] = ((const float4*)b)[j];
#pragma unroll
    for (int kh = 0; kh < 3; ++kh) {
        int ih = 2 * oh - 1 + kh;
        if ((unsigned)ih >= 50u) continue;
#pragma unroll
        for (int kw = 0; kw < 3; ++kw) {
            int iw = 2 * ow - 1 + kw;
            if ((unsigned)iw >= 50u) continue;
            float v = xp[ih * 50 + iw];
            int tap = kh * 3 + kw;
#pragma unroll
            for (int j = 0; j < 8; ++j) {
                float4 ww = wl4[tap * 8 + j];
                a[j].x += v * ww.x; a[j].y += v * ww.y;
                a[j].z += v * ww.z; a[j].w += v * ww.w;
            }
        }
    }
    float4* op = (float4*)(h1 + (size_t)pix * 32);
#pragma unroll
    for (int j = 0; j < 8; ++j) {
        float4 r;
        r.x = fmaxf(a[j].x, 0.f); r.y = fmaxf(a[j].y, 0.f);
        r.z = fmaxf(a[j].z, 0.f); r.w = fmaxf(a[j].w, 0.f);
        op[j] = r;
    }
}

// ---- conv2: h1 -> h2 (bc,13,13,64), relu. lane=pixel, 32 co/thread ---------
__global__ __launch_bounds__(256, 4) void k_conv2(const float* __restrict__ h1,
                                                  const float* __restrict__ w2t,
                                                  const float* __restrict__ b,
                                                  float* __restrict__ h2, int npix) {
    int pix = blockIdx.x * 256 + threadIdx.x;
    if (pix >= npix) return;
    int cog = blockIdx.y;
    int n = pix / 169, p = pix % 169, oh = p / 13, ow = p % 13;
    const float* bb = b + cog * 32;
    float acc[32];
#pragma unroll
    for (int co = 0; co < 32; ++co) acc[co] = bb[co];
    const float* wb = w2t + cog * 9216;
    const float4 zero = {0.f, 0.f, 0.f, 0.f};
#pragma unroll 1
    for (int cc = 0; cc < 8; ++cc) {
        float4 t[9];
#pragma unroll
        for (int kh = 0; kh < 3; ++kh) {
            int ih = 2 * oh - 1 + kh;
#pragma unroll
            for (int kw = 0; kw < 3; ++kw) {
                int iw = 2 * ow - 1 + kw;
                bool ok = ((unsigned)ih < 25u) && ((unsigned)iw < 25u);
                t[kh * 3 + kw] = ok ? *(const float4*)(h1 + (((size_t)n * 25 + ih) * 25 + iw) * 32 + cc * 4)
                                    : zero;
            }
        }
#pragma unroll
        for (int tap = 0; tap < 9; ++tap) {
#pragma unroll
            for (int j = 0; j < 4; ++j) {
                float vj = (j == 0) ? t[tap].x : (j == 1) ? t[tap].y : (j == 2) ? t[tap].z : t[tap].w;
                const float* wp = wb + ((cc * 9 + tap) * 4 + j) * 32;
#pragma unroll
                for (int co = 0; co < 32; ++co) acc[co] = fmaf(vj, wp[co], acc[co]);
            }
        }
    }
    float* op = h2 + (size_t)pix * 64 + cog * 32;
#pragma unroll
    for (int c4 = 0; c4 < 8; ++c4) {
        float4 r = {fmaxf(acc[c4 * 4], 0.f), fmaxf(acc[c4 * 4 + 1], 0.f),
                    fmaxf(acc[c4 * 4 + 2], 0.f), fmaxf(acc[c4 * 4 + 3], 0.f)};
        *(float4*)(op + c4 * 4) = r;
    }
}

// ---- conv3 1x1: h2 -> z. lane=pixel, all 64 co in regs ---------------------
__global__ __launch_bounds__(256, 4) void k_conv3(const float* __restrict__ h2,
                                                  const float* __restrict__ w3t,
                                                  const float* __restrict__ b,
                                                  float* __restrict__ z, int npix) {
    int pix = blockIdx.x * 256 + threadIdx.x;
    if (pix >= npix) return;
    float acc[64];
#pragma unroll
    for (int co = 0; co < 64; ++co) acc[co] = b[co];
    const float4* zp = (const float4*)(h2 + (size_t)pix * 64);
#pragma unroll 1
    for (int cc = 0; cc < 16; ++cc) {
        float4 v = zp[cc];
#pragma unroll
        for (int j = 0; j < 4; ++j) {
            float vj = (j == 0) ? v.x : (j == 1) ? v.y : (j == 2) ? v.z : v.w;
            const float* wp = w3t + (cc * 4 + j) * 64;
#pragma unroll
            for (int co = 0; co < 64; ++co) acc[co] = fmaf(vj, wp[co], acc[co]);
        }
    }
    float* op = z + (size_t)pix * 64;
#pragma unroll
    for (int c4 = 0; c4 < 16; ++c4) {
        float4 r = {acc[c4 * 4], acc[c4 * 4 + 1], acc[c4 * 4 + 2], acc[c4 * 4 + 3]};
        *(float4*)(op + c4 * 4) = r;
    }
}

// ---- VQ: z -> q + loss. codebook via uniform s_loads; same FP order as R2 --
__global__ __launch_bounds__(256, 4) void k_vq(const float* __restrict__ z,
                                               const float* __restrict__ cb,
                                               const float* __restrict__ cn,
                                               float* __restrict__ q,
                                               float* __restrict__ loss, int npix) {
    __shared__ float red[4];
    int tid = threadIdx.x;
    int pix = blockIdx.x * 256 + tid;
    bool active = pix < npix;
    float4 z4[16];
    if (active) {
        const float4* zp = (const float4*)(z + (size_t)pix * 64);
#pragma unroll
        for (int i = 0; i < 16; ++i) z4[i] = zp[i];
    }
    float best = 3.4e38f;
    int bk = 0;
    const float4* cb4 = (const float4*)cb;
    if (active) {
#pragma unroll 1
        for (int k = 0; k < 512; ++k) {
            const float4* cr = cb4 + k * 16;  // uniform index -> s_load
            float s0 = 0.f, s1 = 0.f;
#pragma unroll
            for (int i = 0; i < 16; i += 2) {
                float4 a = z4[i], b0 = cr[i];
                float4 c = z4[i + 1], d = cr[i + 1];
                s0 += a.x * b0.x + a.y * b0.y + a.z * b0.z + a.w * b0.w;
                s1 += c.x * d.x + c.y * d.y + c.z * d.z + c.w * d.w;
            }
            float dd = cn[k] - 2.f * (s0 + s1);
            if (dd < best) { best = dd; bk = k; }
        }
    }
    float lsum = 0.f;
    if (active) {
        float4* qp = (float4*)(q + (size_t)pix * 64);
#pragma unroll
        for (int i = 0; i < 16; ++i) {
            float4 cq = cb4[bk * 16 + i];
            float4 zz = z4[i];
            float dx = cq.x - zz.x, dy = cq.y - zz.y, dz = cq.z - zz.z, dw = cq.w - zz.w;
            lsum += dx * dx + dy * dy + dz * dz + dw * dw;
            qp[i] = cq;
        }
    }
#pragma unroll
    for (int off = 32; off > 0; off >>= 1) lsum += __shfl_down(lsum, off);
    if ((tid & 63) == 0) red[tid >> 6] = lsum;
    __syncthreads();
    if (tid == 0) {
        float t = red[0] + red[1] + red[2] + red[3];
        atomicAdd(loss, t * (1.25f / 11075584.f));  // /(1024*64*13*13)
    }
}

// ---- tconv1: q (13,13,64) -> d1 (25,25,64), relu. lane=quad, 16 co/thread --
__global__ __launch_bounds__(256, 4) void k_tconv1(const float* __restrict__ in,
                                                   const float* __restrict__ wt,
                                                   const float* __restrict__ b,
                                                   float* __restrict__ out, int nquad) {
    int quad = blockIdx.x * 256 + threadIdx.x;
    if (quad >= nquad) return;
    int cog = blockIdx.y;  // 4 groups of 16 co
    int n = quad / 169, r = quad % 169, m = r / 13, mw = r % 13;
    bool bm = (m + 1 < 13), bw = (mw + 1 < 13);
    const float* base = in + (((size_t)n * 13 + m) * 13 + mw) * 64;
    const float* bb = b + cog * 16;
    float a0[16], a1[16], a2[16], a3[16];
#pragma unroll
    for (int co = 0; co < 16; ++co) { float t = bb[co]; a0[co] = t; a1[co] = t; a2[co] = t; a3[co] = t; }
    const float* wb = wt + cog * 9216;
    const float4 zero = {0.f, 0.f, 0.f, 0.f};
#pragma unroll 1
    for (int cc = 0; cc < 16; ++cc) {
        float4 v00 = *(const float4*)(base + cc * 4);
        float4 v01 = bw ? *(const float4*)(base + 64 + cc * 4) : zero;
        float4 v10 = bm ? *(const float4*)(base + 13 * 64 + cc * 4) : zero;
        float4 v11 = (bm && bw) ? *(const float4*)(base + 14 * 64 + cc * 4) : zero;
#pragma unroll
        for (int jh = 0; jh < 3; ++jh) {
#pragma unroll
            for (int jw = 0; jw < 3; ++jw) {
                int tap = jh * 3 + jw;
                float4 v = (jh == 0) ? ((jw == 0) ? v11 : v10)
                                     : ((jw == 0) ? v01 : v00);
#pragma unroll
                for (int j = 0; j < 4; ++j) {
                    float vj = (j == 0) ? v.x : (j == 1) ? v.y : (j == 2) ? v.z : v.w;
                    const float* wp = wb + ((cc * 9 + tap) * 4 + j) * 16;
#pragma unroll
                    for (int co = 0; co < 16; ++co) {
                        if (jh == 1 && jw == 1)      a0[co] = fmaf(vj, wp[co], a0[co]);
                        else if (jh == 1)            a1[co] = fmaf(vj, wp[co], a1[co]);
                        else if (jw == 1)            a2[co] = fmaf(vj, wp[co], a2[co]);
                        else                         a3[co] = fmaf(vj, wp[co], a3[co]);
                    }
                }
            }
        }
    }
    size_t ob = (((size_t)n * 25 + 2 * m) * 25 + 2 * mw) * 64 + cog * 16;
#pragma unroll
    for (int c4 = 0; c4 < 4; ++c4) {
        float4 r = {fmaxf(a0[c4 * 4], 0.f), fmaxf(a0[c4 * 4 + 1], 0.f),
                    fmaxf(a0[c4 * 4 + 2], 0.f), fmaxf(a0[c4 * 4 + 3], 0.f)};
        *(float4*)(out + ob + c4 * 4) = r;
    }
    if (bw) {
#pragma unroll
        for (int c4 = 0; c4 < 4; ++c4) {
            float4 r = {fmaxf(a1[c4 * 4], 0.f), fmaxf(a1[c4 * 4 + 1], 0.f),
                        fmaxf(a1[c4 * 4 + 2], 0.f), fmaxf(a1[c4 * 4 + 3], 0.f)};
            *(float4*)(out + ob + 64 + c4 * 4) = r;
        }
    }
    if (bm) {
#pragma unroll
        for (int c4 = 0; c4 < 4; ++c4) {
            float4 r = {fmaxf(a2[c4 * 4], 0.f), fmaxf(a2[c4 * 4 + 1], 0.f),
                        fmaxf(a2[c4 * 4 + 2], 0.f), fmaxf(a2[c4 * 4 + 3], 0.f)};
            *(float4*)(out + ob + 25 * 64 + c4 * 4) = r;
        }
    }
    if (bm && bw) {
#pragma unroll
        for (int c4 = 0; c4 < 4; ++c4) {
            float4 r = {fmaxf(a3[c4 * 4], 0.f), fmaxf(a3[c4 * 4 + 1], 0.f),
                        fmaxf(a3[c4 * 4 + 2], 0.f), fmaxf(a3[c4 * 4 + 3], 0.f)};
            *(float4*)(out + ob + 26 * 64 + c4 * 4) = r;
        }
    }
}

// ---- tconv2: d1 (25,25,64) -> d2 (50,50,32), relu. lane=quad, 16 co/thread -
__global__ __launch_bounds__(256, 4) void k_tconv2(const float* __restrict__ in,
                                                   const float* __restrict__ wt,
                                                   const float* __restrict__ b,
                                                   float* __restrict__ out, int nquad) {
    int quad = blockIdx.x * 256 + threadIdx.x;
    if (quad >= nquad) return;
    int cog = blockIdx.y;  // 2 groups of 16 co
    int n = quad / 625, r = quad % 625, m = r / 25, mw = r % 25;
    bool bm = (m + 1 < 25), bw = (mw + 1 < 25);
    const float* base = in + (((size_t)n * 25 + m) * 25 + mw) * 64;
    const float* bb = b + cog * 16;
    float a0[16], a1[16], a2[16], a3[16];
#pragma unroll
    for (int co = 0; co < 16; ++co) { float t = bb[co]; a0[co] = t; a1[co] = t; a2[co] = t; a3[co] = t; }
    const float* wb = wt + cog * 9216;
    const float4 zero = {0.f, 0.f, 0.f, 0.f};
#pragma unroll 1
    for (int cc = 0; cc < 16; ++cc) {
        float4 v00 = *(const float4*)(base + cc * 4);
        float4 v01 = bw ? *(const float4*)(base + 64 + cc * 4) : zero;
        float4 v10 = bm ? *(const float4*)(base + 25 * 64 + cc * 4) : zero;
        float4 v11 = (bm && bw) ? *(const float4*)(base + 26 * 64 + cc * 4) : zero;
#pragma unroll
        for (int jh = 0; jh < 3; ++jh) {
#pragma unroll
            for (int jw = 0; jw < 3; ++jw) {
                int tap = jh * 3 + jw;
                float4 v = (jh == 0) ? ((jw == 0) ? v11 : v10)
                                     : ((jw == 0) ? v01 : v00);
#pragma unroll
                for (int j = 0; j < 4; ++j) {
                    float vj = (j == 0) ? v.x : (j == 1) ? v.y : (j == 2) ? v.z : v.w;
                    const float* wp = wb + ((cc * 9 + tap) * 4 + j) * 16;
#pragma unroll
                    for (int co = 0; co < 16; ++co) {
                        if (jh == 1 && jw == 1)      a0[co] = fmaf(vj, wp[co], a0[co]);
                        else if (jh == 1)            a1[co] = fmaf(vj, wp[co], a1[co]);
                        else if (jw == 1)            a2[co] = fmaf(vj, wp[co], a2[co]);
                        else                         a3[co] = fmaf(vj, wp[co], a3[co]);
                    }
                }
            }
        }
    }
    size_t ob = (((size_t)n * 50 + 2 * m) * 50 + 2 * mw) * 32 + cog * 16;
#pragma unroll
    for (int c4 = 0; c4 < 4; ++c4) {
        float4 r0 = {fmaxf(a0[c4 * 4], 0.f), fmaxf(a0[c4 * 4 + 1], 0.f),
                     fmaxf(a0[c4 * 4 + 2], 0.f), fmaxf(a0[c4 * 4 + 3], 0.f)};
        *(float4*)(out + ob + c4 * 4) = r0;
        float4 r1 = {fmaxf(a1[c4 * 4], 0.f), fmaxf(a1[c4 * 4 + 1], 0.f),
                     fmaxf(a1[c4 * 4 + 2], 0.f), fmaxf(a1[c4 * 4 + 3], 0.f)};
        *(float4*)(out + ob + 32 + c4 * 4) = r1;
        float4 r2 = {fmaxf(a2[c4 * 4], 0.f), fmaxf(a2[c4 * 4 + 1], 0.f),
                     fmaxf(a2[c4 * 4 + 2], 0.f), fmaxf(a2[c4 * 4 + 3], 0.f)};
        *(float4*)(out + ob + 50 * 32 + c4 * 4) = r2;
        float4 r3 = {fmaxf(a3[c4 * 4], 0.f), fmaxf(a3[c4 * 4 + 1], 0.f),
                     fmaxf(a3[c4 * 4 + 2], 0.f), fmaxf(a3[c4 * 4 + 3], 0.f)};
        *(float4*)(out + ob + 51 * 32 + c4 * 4) = r3;
    }
}

// ---- convf: d2 (bc,50,50,32) -> out (bc,50,50), sigmoid --------------------
__global__ __launch_bounds__(256) void k_convf(const float* __restrict__ in,
                                               const float* __restrict__ w,  // dw3 (1,32,3,3)
                                               const float* __restrict__ b,
                                               float* __restrict__ out, int total) {
    __shared__ float4 wl4[72];  // [tap9][ci32] f4
    float* wl = (float*)wl4;
    int tid = threadIdx.x;
    for (int t = tid; t < 288; t += 256) {
        int tap = t >> 5, ci = t & 31;
        wl[t] = w[ci * 9 + tap];
    }
    __syncthreads();
    int pix = blockIdx.x * 256 + tid;
    if (pix >= total) return;
    int n = pix / 2500, p = pix % 2500, oh = p / 50, ow = p % 50;
    float acc = b[0];
#pragma unroll
    for (int kh = 0; kh < 3; ++kh) {
        int ih = oh - 1 + kh;
        if ((unsigned)ih >= 50u) continue;
#pragma unroll
        for (int kw = 0; kw < 3; ++kw) {
            int iw = ow - 1 + kw;
            if ((unsigned)iw >= 50u) continue;
            int tap = kh * 3 + kw;
            const float4* ip = (const float4*)(in + (((size_t)n * 50 + ih) * 50 + iw) * 32);
#pragma unroll
            for (int cc = 0; cc < 8; ++cc) {
                float4 v = ip[cc];
                float4 ww = wl4[tap * 8 + cc];
                acc += v.x * ww.x + v.y * ww.y + v.z * ww.z + v.w * ww.w;
            }
        }
    }
    out[pix] = 1.f / (1.f + expf(-acc));
}

extern "C" void kernel_launch(void* const* d_in, const int* in_sizes, int n_in,
                              void* d_out, int out_size, void* d_ws, size_t ws_size,
                              hipStream_t stream) {
    const float* x   = (const float*)d_in[0];
    const float* ew1 = (const float*)d_in[1];
    const float* eb1 = (const float*)d_in[2];
    const float* ew2 = (const float*)d_in[3];
    const float* eb2 = (const float*)d_in[4];
    const float* ew3 = (const float*)d_in[5];
    const float* eb3 = (const float*)d_in[6];
    const float* cb  = (const float*)d_in[7];
    const float* dw1 = (const float*)d_in[8];
    const float* db1 = (const float*)d_in[9];
    const float* dw2 = (const float*)d_in[10];
    const float* db2 = (const float*)d_in[11];
    const float* dw3 = (const float*)d_in[12];
    const float* db3 = (const float*)d_in[13];
    float* out = (float*)d_out;
    float* loss = out + 2560000;

    float* ws   = (float*)d_ws;
    float* w2t  = ws;              // 18432
    float* w3t  = ws + 18432;      // 4096
    float* wt1  = ws + 22528;      // 36864
    float* wt2  = ws + 59392;      // 18432
    float* cn   = ws + 77824;      // 512
    const size_t tw_floats = 78336;

    const int B = 1024;
    const size_t A_per = 80000, B_per = 40000;  // floats per image
    size_t avail = (ws_size / 4 > tw_floats) ? ws_size / 4 - tw_floats : 0;
    int BC = (int)(avail / (A_per + B_per));
    if (BC > B) BC = B;
    if (BC < 1) BC = 1;
    float* regA = ws + tw_floats;
    float* regB = regA + (size_t)BC * A_per;

    k_zero<<<1, 64, 0, stream>>>(loss);
    k_prep_w2t<<<72, 256, 0, stream>>>(ew2, w2t);
    k_prep_w3t<<<16, 256, 0, stream>>>(ew3, w3t);
    k_prep_wt1<<<144, 256, 0, stream>>>(dw1, wt1);
    k_prep_wt2<<<72, 256, 0, stream>>>(dw2, wt2);
    k_prep_cn <<<2, 256, 0, stream>>>(cb, cn);

    for (int n0 = 0; n0 < B; n0 += BC) {
        int bc = (B - n0 < BC) ? (B - n0) : BC;
        const float* xch = x + (size_t)n0 * 2500;

        int t1 = bc * 625;   // conv1: x -> h1 (regB)
        k_conv1<<<(t1 + 255) / 256, 256, 0, stream>>>(xch, ew1, eb1, regB, t1);

        int npix = bc * 169;
        dim3 g2((npix + 255) / 256, 2);  // conv2: regB -> regA (h2)
        k_conv2<<<g2, 256, 0, stream>>>(regB, w2t, eb2, regA, npix);

        // conv3: regA -> regB (z)
        k_conv3<<<(npix + 255) / 256, 256, 0, stream>>>(regA, w3t, eb3, regB, npix);

        // vq: regB (z) -> regA (q)
        k_vq<<<(npix + 255) / 256, 256, 0, stream>>>(regB, cb, cn, regA, loss, npix);

        dim3 g4((npix + 255) / 256, 4);  // tconv1: regA (q) -> regB (d1)
        k_tconv1<<<g4, 256, 0, stream>>>(regA, wt1, db1, regB, npix);

        int nq2 = bc * 625;
        dim3 g5((nq2 + 255) / 256, 2);   // tconv2: regB (d1) -> regA (d2)
        k_tconv2<<<g5, 256, 0, stream>>>(regB, wt2, db2, regA, nq2);

        int t6 = bc * 2500;  // convf: regA -> out
        k_convf<<<(t6 + 255) / 256, 256, 0, stream>>>(regA, dw3, db3, out + (size_t)n0 * 2500, t6);
    }
}

// Round 4
// 2905.908 us; speedup vs baseline: 8.0928x; 1.1302x over previous
//
#include <hip/hip_runtime.h>
#include <math.h>

// ---------------------------------------------------------------------------
// VQ-VAE forward, fp32, NHWC intermediates.
// R4: latency fixes. Input prefetch (register double-buffer) in conv2/conv3/
// tconvs; VQ split into 2 code-slices (2x blocks) + merge kernel;
// launch_bounds(256,3) for register headroom so the compiler can pipeline
// the uniform weight s_load streams.
//  x (1024,1,50,50)
//  conv1 k3s2p1+relu -> h1 (n,25,25,32)   [regB]
//  conv2 k3s2p1+relu -> h2 (n,13,13,64)   [regA]
//  conv3 1x1         -> z  (n,13,13,64)   [regB]
//  VQ 512x64 (slice+merge) -> q (n,13,13,64) [regA] + loss atomic
//  tconv1 13->25+relu-> d1 (n,25,25,64)   [regB]
//  tconv2 25->50+relu-> d2 (n,50,50,32)   [regA]
//  convf k3s1p1+sigm -> out (n,50,50)
// ---------------------------------------------------------------------------

__global__ __launch_bounds__(64) void k_zero(float* __restrict__ p) {
    if (threadIdx.x == 0 && blockIdx.x == 0) *p = 0.f;
}

// ---- weight transpose preps ------------------------------------------------
// w2t: [cog2][cc8][tap9][j4][co32] <- ew2[co_g=cog*32+co][ci=cc*4+j][tap]
__global__ __launch_bounds__(256) void k_prep_w2t(const float* __restrict__ w,
                                                  float* __restrict__ o) {
    int i = blockIdx.x * 256 + threadIdx.x;  // 18432
    int co = i & 31, j = (i >> 5) & 3, tap = (i >> 7) % 9;
    int q = (i >> 7) / 9, cc = q & 7, cog = q >> 3;
    o[i] = w[((cog * 32 + co) * 32 + cc * 4 + j) * 9 + tap];
}
// w3t: [ci64][co64] <- ew3[co][ci]
__global__ __launch_bounds__(256) void k_prep_w3t(const float* __restrict__ w,
                                                  float* __restrict__ o) {
    int i = blockIdx.x * 256 + threadIdx.x;  // 4096
    int co = i & 63, ci = i >> 6;
    o[i] = w[co * 64 + ci];
}
// wt1: [cog4][cc16][tap9][j4][co16] <- dw1[co_g=cog*16+co][ci=cc*4+j][tap]
__global__ __launch_bounds__(256) void k_prep_wt1(const float* __restrict__ w,
                                                  float* __restrict__ o) {
    int i = blockIdx.x * 256 + threadIdx.x;  // 36864
    int co = i & 15, j = (i >> 4) & 3, tap = (i >> 6) % 9;
    int q = (i >> 6) / 9, cc = q & 15, cog = q >> 4;
    o[i] = w[((cog * 16 + co) * 64 + cc * 4 + j) * 9 + tap];
}
// wt2: [cog2][cc16][tap9][j4][co16] <- dw2[co_g=cog*16+co][ci=cc*4+j][tap]
__global__ __launch_bounds__(256) void k_prep_wt2(const float* __restrict__ w,
                                                  float* __restrict__ o) {
    int i = blockIdx.x * 256 + threadIdx.x;  // 18432
    int co = i & 15, j = (i >> 4) & 3, tap = (i >> 6) % 9;
    int q = (i >> 6) / 9, cc = q & 15, cog = q >> 4;
    o[i] = w[((cog * 16 + co) * 64 + cc * 4 + j) * 9 + tap];
}
// cn[k] = ||cb[k]||^2
__global__ __launch_bounds__(256) void k_prep_cn(const float* __restrict__ cb,
                                                 float* __restrict__ cn) {
    int k = blockIdx.x * 256 + threadIdx.x;  // 512
    const float* r = cb + k * 64;
    float s = 0.f;
#pragma unroll
    for (int c = 0; c < 64; ++c) s += r[c] * r[c];
    cn[k] = s;
}

// ---- conv1: x (bc,50,50) -> h1 (bc,25,25,32), relu -------------------------
__global__ __launch_bounds__(256) void k_conv1(const float* __restrict__ x,
                                               const float* __restrict__ w,   // ew1 OIHW
                                               const float* __restrict__ b,
                                               float* __restrict__ h1, int total) {
    __shared__ float4 wl4[72];  // [tap9][co32] as f4
    float* wl = (float*)wl4;
    int tid = threadIdx.x;
    for (int t = tid; t < 288; t += 256) {
        int tap = t >> 5, co = t & 31;
        wl[t] = w[co * 9 + tap];
    }
    __syncthreads();
    int pix = blockIdx.x * 256 + tid;
    if (pix >= total) return;
    int n = pix / 625, p = pix % 625, oh = p / 25, ow = p % 25;
    const float* xp = x + (size_t)n * 2500;
    float4 a[8];
#pragma unroll
    for (int j = 0; j < 8; ++j) a[j] = ((const float4*)b)[j];
#pragma unroll
    for (int kh = 0; kh < 3; ++kh) {
        int ih = 2 * oh - 1 + kh;
        if ((unsigned)ih >= 50u) continue;
#pragma unroll
        for (int kw = 0; kw < 3; ++kw) {
            int iw = 2 * ow - 1 + kw;
            if ((unsigned)iw >= 50u) continue;
            float v = xp[ih * 50 + iw];
            int tap = kh * 3 + kw;
#pragma unroll
            for (int j = 0; j < 8; ++j) {
                float4 ww = wl4[tap * 8 + j];
                a[j].x += v * ww.x; a[j].y += v * ww.y;
                a[j].z += v * ww.z; a[j].w += v * ww.w;
            }
        }
    }
    float4* op = (float4*)(h1 + (size_t)pix * 32);
#pragma unroll
    for (int j = 0; j < 8; ++j) {
        float4 r;
        r.x = fmaxf(a[j].x, 0.f); r.y = fmaxf(a[j].y, 0.f);
        r.z = fmaxf(a[j].z, 0.f); r.w = fmaxf(a[j].w, 0.f);
        op[j] = r;
    }
}

// ---- conv2: h1 -> h2 (bc,13,13,64), relu. lane=pixel, 32 co/thread ---------
__global__ __launch_bounds__(256, 3) void k_conv2(const float* __restrict__ h1,
                                                  const float* __restrict__ w2t,
                                                  const float* __restrict__ b,
                                                  float* __restrict__ h2, int npix) {
    int pix = blockIdx.x * 256 + threadIdx.x;
    if (pix >= npix) return;
    int cog = blockIdx.y;
    int n = pix / 169, p = pix % 169, oh = p / 13, ow = p % 13;
    const float* bb = b + cog * 32;
    float acc[32];
#pragma unroll
    for (int co = 0; co < 32; ++co) acc[co] = bb[co];
    const float* wb = w2t + cog * 9216;
    const float4 zero = {0.f, 0.f, 0.f, 0.f};
    auto ldcc = [&](float4* dst, int cc) {
#pragma unroll
        for (int kh = 0; kh < 3; ++kh) {
            int ih = 2 * oh - 1 + kh;
#pragma unroll
            for (int kw = 0; kw < 3; ++kw) {
                int iw = 2 * ow - 1 + kw;
                bool ok = ((unsigned)ih < 25u) && ((unsigned)iw < 25u);
                dst[kh * 3 + kw] = ok ? *(const float4*)(h1 + (((size_t)n * 25 + ih) * 25 + iw) * 32 + cc * 4)
                                      : zero;
            }
        }
    };
    float4 t[9], tn[9];
    ldcc(t, 0);
#pragma unroll 1
    for (int cc = 0; cc < 8; ++cc) {
        if (cc < 7) ldcc(tn, cc + 1);  // prefetch next chunk's inputs
#pragma unroll
        for (int tap = 0; tap < 9; ++tap) {
#pragma unroll
            for (int j = 0; j < 4; ++j) {
                float vj = (j == 0) ? t[tap].x : (j == 1) ? t[tap].y : (j == 2) ? t[tap].z : t[tap].w;
                const float* wp = wb + ((cc * 9 + tap) * 4 + j) * 32;
#pragma unroll
                for (int co = 0; co < 32; ++co) acc[co] = fmaf(vj, wp[co], acc[co]);
            }
        }
        if (cc < 7) {
#pragma unroll
            for (int i = 0; i < 9; ++i) t[i] = tn[i];
        }
    }
    float* op = h2 + (size_t)pix * 64 + cog * 32;
#pragma unroll
    for (int c4 = 0; c4 < 8; ++c4) {
        float4 r = {fmaxf(acc[c4 * 4], 0.f), fmaxf(acc[c4 * 4 + 1], 0.f),
                    fmaxf(acc[c4 * 4 + 2], 0.f), fmaxf(acc[c4 * 4 + 3], 0.f)};
        *(float4*)(op + c4 * 4) = r;
    }
}

// ---- conv3 1x1: h2 -> z. lane=pixel, all 64 co in regs ---------------------
__global__ __launch_bounds__(256, 3) void k_conv3(const float* __restrict__ h2,
                                                  const float* __restrict__ w3t,
                                                  const float* __restrict__ b,
                                                  float* __restrict__ z, int npix) {
    int pix = blockIdx.x * 256 + threadIdx.x;
    if (pix >= npix) return;
    float acc[64];
#pragma unroll
    for (int co = 0; co < 64; ++co) acc[co] = b[co];
    const float4* zp = (const float4*)(h2 + (size_t)pix * 64);
    float4 v = zp[0];
#pragma unroll 1
    for (int cc = 0; cc < 16; ++cc) {
        float4 vn;
        if (cc < 15) vn = zp[cc + 1];  // prefetch
#pragma unroll
        for (int j = 0; j < 4; ++j) {
            float vj = (j == 0) ? v.x : (j == 1) ? v.y : (j == 2) ? v.z : v.w;
            const float* wp = w3t + (cc * 4 + j) * 64;
#pragma unroll
            for (int co = 0; co < 64; ++co) acc[co] = fmaf(vj, wp[co], acc[co]);
        }
        if (cc < 15) v = vn;
    }
    float* op = z + (size_t)pix * 64;
#pragma unroll
    for (int c4 = 0; c4 < 16; ++c4) {
        float4 r = {acc[c4 * 4], acc[c4 * 4 + 1], acc[c4 * 4 + 2], acc[c4 * 4 + 3]};
        *(float4*)(op + c4 * 4) = r;
    }
}

// ---- VQ slice: scan 256 codes, write per-pixel (bestd, bestk) --------------
// grid (ceil(npix/256), 2); slice s covers codes [s*256, s*256+256)
__global__ __launch_bounds__(256, 3) void k_vq_slice(const float* __restrict__ z,
                                                     const float* __restrict__ cb,
                                                     const float* __restrict__ cn,
                                                     float* __restrict__ bestd,
                                                     int* __restrict__ bestk, int npix) {
    int pix = blockIdx.x * 256 + threadIdx.x;
    if (pix >= npix) return;
    int k0 = blockIdx.y * 256;
    float4 z4[16];
    const float4* zp = (const float4*)(z + (size_t)pix * 64);
#pragma unroll
    for (int i = 0; i < 16; ++i) z4[i] = zp[i];
    const float4* cb4 = (const float4*)cb + (size_t)k0 * 16;
    const float* cns = cn + k0;
    float best = 3.4e38f;
    int bk = k0;
    for (int k = 0; k < 256; ++k) {  // compiler free to unroll/pipeline
        const float4* cr = cb4 + k * 16;  // uniform index
        float s0 = 0.f, s1 = 0.f;
#pragma unroll
        for (int i = 0; i < 16; i += 2) {
            float4 a = z4[i], b0 = cr[i];
            float4 c = z4[i + 1], d = cr[i + 1];
            s0 += a.x * b0.x + a.y * b0.y + a.z * b0.z + a.w * b0.w;
            s1 += c.x * d.x + c.y * d.y + c.z * d.z + c.w * d.w;
        }
        float dd = cns[k] - 2.f * (s0 + s1);
        if (dd < best) { best = dd; bk = k0 + k; }
    }
    bestd[(size_t)blockIdx.y * npix + pix] = best;
    bestk[(size_t)blockIdx.y * npix + pix] = bk;
}

// ---- VQ merge: pick winner, write q, accumulate loss -----------------------
__global__ __launch_bounds__(256) void k_vq_merge(const float* __restrict__ z,
                                                  const float* __restrict__ cb,
                                                  const float* __restrict__ bestd,
                                                  const int* __restrict__ bestk,
                                                  float* __restrict__ q,
                                                  float* __restrict__ loss, int npix) {
    __shared__ float red[4];
    int tid = threadIdx.x;
    int pix = blockIdx.x * 256 + tid;
    bool active = pix < npix;
    float lsum = 0.f;
    if (active) {
        float d0 = bestd[pix], d1 = bestd[(size_t)npix + pix];
        int kk0 = bestk[pix], kk1 = bestk[(size_t)npix + pix];
        int bk = (d1 < d0) ? kk1 : kk0;  // strict < : slice0 (lower k) wins ties
        const float4* cb4 = (const float4*)cb;
        const float4* zp = (const float4*)(z + (size_t)pix * 64);
        float4* qp = (float4*)(q + (size_t)pix * 64);
#pragma unroll
        for (int i = 0; i < 16; ++i) {
            float4 cq = cb4[bk * 16 + i];
            float4 zz = zp[i];
            float dx = cq.x - zz.x, dy = cq.y - zz.y, dz = cq.z - zz.z, dw = cq.w - zz.w;
            lsum += dx * dx + dy * dy + dz * dz + dw * dw;
            qp[i] = cq;
        }
    }
#pragma unroll
    for (int off = 32; off > 0; off >>= 1) lsum += __shfl_down(lsum, off);
    if ((tid & 63) == 0) red[tid >> 6] = lsum;
    __syncthreads();
    if (tid == 0) {
        float t = red[0] + red[1] + red[2] + red[3];
        atomicAdd(loss, t * (1.25f / 11075584.f));  // /(1024*64*13*13)
    }
}

// ---- tconv1: q (13,13,64) -> d1 (25,25,64), relu. lane=quad, 16 co/thread --
__global__ __launch_bounds__(256, 3) void k_tconv1(const float* __restrict__ in,
                                                   const float* __restrict__ wt,
                                                   const float* __restrict__ b,
                                                   float* __restrict__ out, int nquad) {
    int quad = blockIdx.x * 256 + threadIdx.x;
    if (quad >= nquad) return;
    int cog = blockIdx.y;  // 4 groups of 16 co
    int n = quad / 169, r = quad % 169, m = r / 13, mw = r % 13;
    bool bm = (m + 1 < 13), bw = (mw + 1 < 13);
    const float* base = in + (((size_t)n * 13 + m) * 13 + mw) * 64;
    const float* bb = b + cog * 16;
    float a0[16], a1[16], a2[16], a3[16];
#pragma unroll
    for (int co = 0; co < 16; ++co) { float t = bb[co]; a0[co] = t; a1[co] = t; a2[co] = t; a3[co] = t; }
    const float* wb = wt + cog * 9216;
    const float4 zero = {0.f, 0.f, 0.f, 0.f};
    auto ldcc = [&](float4& q00, float4& q01, float4& q10, float4& q11, int cc) {
        q00 = *(const float4*)(base + cc * 4);
        q01 = bw ? *(const float4*)(base + 64 + cc * 4) : zero;
        q10 = bm ? *(const float4*)(base + 13 * 64 + cc * 4) : zero;
        q11 = (bm && bw) ? *(const float4*)(base + 14 * 64 + cc * 4) : zero;
    };
    float4 p00, p01, p10, p11;
    ldcc(p00, p01, p10, p11, 0);
#pragma unroll 1
    for (int cc = 0; cc < 16; ++cc) {
        float4 v00 = p00, v01 = p01, v10 = p10, v11 = p11;
        if (cc < 15) ldcc(p00, p01, p10, p11, cc + 1);  // prefetch
#pragma unroll
        for (int jh = 0; jh < 3; ++jh) {
#pragma unroll
            for (int jw = 0; jw < 3; ++jw) {
                int tap = jh * 3 + jw;
                float4 v = (jh == 0) ? ((jw == 0) ? v11 : v10)
                                     : ((jw == 0) ? v01 : v00);
#pragma unroll
                for (int j = 0; j < 4; ++j) {
                    float vj = (j == 0) ? v.x : (j == 1) ? v.y : (j == 2) ? v.z : v.w;
                    const float* wp = wb + ((cc * 9 + tap) * 4 + j) * 16;
#pragma unroll
                    for (int co = 0; co < 16; ++co) {
                        if (jh == 1 && jw == 1)      a0[co] = fmaf(vj, wp[co], a0[co]);
                        else if (jh == 1)            a1[co] = fmaf(vj, wp[co], a1[co]);
                        else if (jw == 1)            a2[co] = fmaf(vj, wp[co], a2[co]);
                        else                         a3[co] = fmaf(vj, wp[co], a3[co]);
                    }
                }
            }
        }
    }
    size_t ob = (((size_t)n * 25 + 2 * m) * 25 + 2 * mw) * 64 + cog * 16;
#pragma unroll
    for (int c4 = 0; c4 < 4; ++c4) {
        float4 r = {fmaxf(a0[c4 * 4], 0.f), fmaxf(a0[c4 * 4 + 1], 0.f),
                    fmaxf(a0[c4 * 4 + 2], 0.f), fmaxf(a0[c4 * 4 + 3], 0.f)};
        *(float4*)(out + ob + c4 * 4) = r;
    }
    if (bw) {
#pragma unroll
        for (int c4 = 0; c4 < 4; ++c4) {
            float4 r = {fmaxf(a1[c4 * 4], 0.f), fmaxf(a1[c4 * 4 + 1], 0.f),
                        fmaxf(a1[c4 * 4 + 2], 0.f), fmaxf(a1[c4 * 4 + 3], 0.f)};
            *(float4*)(out + ob + 64 + c4 * 4) = r;
        }
    }
    if (bm) {
#pragma unroll
        for (int c4 = 0; c4 < 4; ++c4) {
            float4 r = {fmaxf(a2[c4 * 4], 0.f), fmaxf(a2[c4 * 4 + 1], 0.f),
                        fmaxf(a2[c4 * 4 + 2], 0.f), fmaxf(a2[c4 * 4 + 3], 0.f)};
            *(float4*)(out + ob + 25 * 64 + c4 * 4) = r;
        }
    }
    if (bm && bw) {
#pragma unroll
        for (int c4 = 0; c4 < 4; ++c4) {
            float4 r = {fmaxf(a3[c4 * 4], 0.f), fmaxf(a3[c4 * 4 + 1], 0.f),
                        fmaxf(a3[c4 * 4 + 2], 0.f), fmaxf(a3[c4 * 4 + 3], 0.f)};
            *(float4*)(out + ob + 26 * 64 + c4 * 4) = r;
        }
    }
}

// ---- tconv2: d1 (25,25,64) -> d2 (50,50,32), relu. lane=quad, 16 co/thread -
__global__ __launch_bounds__(256, 3) void k_tconv2(const float* __restrict__ in,
                                                   const float* __restrict__ wt,
                                                   const float* __restrict__ b,
                                                   float* __restrict__ out, int nquad) {
    int quad = blockIdx.x * 256 + threadIdx.x;
    if (quad >= nquad) return;
    int cog = blockIdx.y;  // 2 groups of 16 co
    int n = quad / 625, r = quad % 625, m = r / 25, mw = r % 25;
    bool bm = (m + 1 < 25), bw = (mw + 1 < 25);
    const float* base = in + (((size_t)n * 25 + m) * 25 + mw) * 64;
    const float* bb = b + cog * 16;
    float a0[16], a1[16], a2[16], a3[16];
#pragma unroll
    for (int co = 0; co < 16; ++co) { float t = bb[co]; a0[co] = t; a1[co] = t; a2[co] = t; a3[co] = t; }
    const float* wb = wt + cog * 9216;
    const float4 zero = {0.f, 0.f, 0.f, 0.f};
    auto ldcc = [&](float4& q00, float4& q01, float4& q10, float4& q11, int cc) {
        q00 = *(const float4*)(base + cc * 4);
        q01 = bw ? *(const float4*)(base + 64 + cc * 4) : zero;
        q10 = bm ? *(const float4*)(base + 25 * 64 + cc * 4) : zero;
        q11 = (bm && bw) ? *(const float4*)(base + 26 * 64 + cc * 4) : zero;
    };
    float4 p00, p01, p10, p11;
    ldcc(p00, p01, p10, p11, 0);
#pragma unroll 1
    for (int cc = 0; cc < 16; ++cc) {
        float4 v00 = p00, v01 = p01, v10 = p10, v11 = p11;
        if (cc < 15) ldcc(p00, p01, p10, p11, cc + 1);  // prefetch
#pragma unroll
        for (int jh = 0; jh < 3; ++jh) {
#pragma unroll
            for (int jw = 0; jw < 3; ++jw) {
                int tap = jh * 3 + jw;
                float4 v = (jh == 0) ? ((jw == 0) ? v11 : v10)
                                     : ((jw == 0) ? v01 : v00);
#pragma unroll
                for (int j = 0; j < 4; ++j) {
                    float vj = (j == 0) ? v.x : (j == 1) ? v.y : (j == 2) ? v.z : v.w;
                    const float* wp = wb + ((cc * 9 + tap) * 4 + j) * 16;
#pragma unroll
                    for (int co = 0; co < 16; ++co) {
                        if (jh == 1 && jw == 1)      a0[co] = fmaf(vj, wp[co], a0[co]);
                        else if (jh == 1)            a1[co] = fmaf(vj, wp[co], a1[co]);
                        else if (jw == 1)            a2[co] = fmaf(vj, wp[co], a2[co]);
                        else                         a3[co] = fmaf(vj, wp[co], a3[co]);
                    }
                }
            }
        }
    }
    size_t ob = (((size_t)n * 50 + 2 * m) * 50 + 2 * mw) * 32 + cog * 16;
#pragma unroll
    for (int c4 = 0; c4 < 4; ++c4) {
        float4 r0 = {fmaxf(a0[c4 * 4], 0.f), fmaxf(a0[c4 * 4 + 1], 0.f),
                     fmaxf(a0[c4 * 4 + 2], 0.f), fmaxf(a0[c4 * 4 + 3], 0.f)};
        *(float4*)(out + ob + c4 * 4) = r0;
        float4 r1 = {fmaxf(a1[c4 * 4], 0.f), fmaxf(a1[c4 * 4 + 1], 0.f),
                     fmaxf(a1[c4 * 4 + 2], 0.f), fmaxf(a1[c4 * 4 + 3], 0.f)};
        *(float4*)(out + ob + 32 + c4 * 4) = r1;
        float4 r2 = {fmaxf(a2[c4 * 4], 0.f), fmaxf(a2[c4 * 4 + 1], 0.f),
                     fmaxf(a2[c4 * 4 + 2], 0.f), fmaxf(a2[c4 * 4 + 3], 0.f)};
        *(float4*)(out + ob + 50 * 32 + c4 * 4) = r2;
        float4 r3 = {fmaxf(a3[c4 * 4], 0.f), fmaxf(a3[c4 * 4 + 1], 0.f),
                     fmaxf(a3[c4 * 4 + 2], 0.f), fmaxf(a3[c4 * 4 + 3], 0.f)};
        *(float4*)(out + ob + 51 * 32 + c4 * 4) = r3;
    }
}

// ---- convf: d2 (bc,50,50,32) -> out (bc,50,50), sigmoid --------------------
__global__ __launch_bounds__(256) void k_convf(const float* __restrict__ in,
                                               const float* __restrict__ w,  // dw3 (1,32,3,3)
                                               const float* __restrict__ b,
                                               float* __restrict__ out, int total) {
    __shared__ float4 wl4[72];  // [tap9][ci32] f4
    float* wl = (float*)wl4;
    int tid = threadIdx.x;
    for (int t = tid; t < 288; t += 256) {
        int tap = t >> 5, ci = t & 31;
        wl[t] = w[ci * 9 + tap];
    }
    __syncthreads();
    int pix = blockIdx.x * 256 + tid;
    if (pix >= total) return;
    int n = pix / 2500, p = pix % 2500, oh = p / 50, ow = p % 50;
    float acc = b[0];
#pragma unroll
    for (int kh = 0; kh < 3; ++kh) {
        int ih = oh - 1 + kh;
        if ((unsigned)ih >= 50u) continue;
#pragma unroll
        for (int kw = 0; kw < 3; ++kw) {
            int iw = ow - 1 + kw;
            if ((unsigned)iw >= 50u) continue;
            int tap = kh * 3 + kw;
            const float4* ip = (const float4*)(in + (((size_t)n * 50 + ih) * 50 + iw) * 32);
#pragma unroll
            for (int cc = 0; cc < 8; ++cc) {
                float4 v = ip[cc];
                float4 ww = wl4[tap * 8 + cc];
                acc += v.x * ww.x + v.y * ww.y + v.z * ww.z + v.w * ww.w;
            }
        }
    }
    out[pix] = 1.f / (1.f + expf(-acc));
}

extern "C" void kernel_launch(void* const* d_in, const int* in_sizes, int n_in,
                              void* d_out, int out_size, void* d_ws, size_t ws_size,
                              hipStream_t stream) {
    const float* x   = (const float*)d_in[0];
    const float* ew1 = (const float*)d_in[1];
    const float* eb1 = (const float*)d_in[2];
    const float* ew2 = (const float*)d_in[3];
    const float* eb2 = (const float*)d_in[4];
    const float* ew3 = (const float*)d_in[5];
    const float* eb3 = (const float*)d_in[6];
    const float* cb  = (const float*)d_in[7];
    const float* dw1 = (const float*)d_in[8];
    const float* db1 = (const float*)d_in[9];
    const float* dw2 = (const float*)d_in[10];
    const float* db2 = (const float*)d_in[11];
    const float* dw3 = (const float*)d_in[12];
    const float* db3 = (const float*)d_in[13];
    float* out = (float*)d_out;
    float* loss = out + 2560000;

    float* ws   = (float*)d_ws;
    float* w2t  = ws;              // 18432
    float* w3t  = ws + 18432;      // 4096
    float* wt1  = ws + 22528;      // 36864
    float* wt2  = ws + 59392;      // 18432
    float* cn   = ws + 77824;      // 512
    const size_t tw_floats = 78336;

    const int B = 1024;
    // per image: regA 80000 + regB 40000 + bestd 2*169 + bestk 2*169
    const size_t A_per = 80000, B_per = 40000, V_per = 676;
    size_t avail = (ws_size / 4 > tw_floats) ? ws_size / 4 - tw_floats : 0;
    int BC = (int)(avail / (A_per + B_per + V_per));
    if (BC > B) BC = B;
    if (BC < 1) BC = 1;
    float* regA  = ws + tw_floats;
    float* regB  = regA + (size_t)BC * A_per;
    float* bestd = regB + (size_t)BC * B_per;            // 2*BC*169 floats
    int*   bestk = (int*)(bestd + (size_t)2 * BC * 169); // 2*BC*169 ints

    k_zero<<<1, 64, 0, stream>>>(loss);
    k_prep_w2t<<<72, 256, 0, stream>>>(ew2, w2t);
    k_prep_w3t<<<16, 256, 0, stream>>>(ew3, w3t);
    k_prep_wt1<<<144, 256, 0, stream>>>(dw1, wt1);
    k_prep_wt2<<<72, 256, 0, stream>>>(dw2, wt2);
    k_prep_cn <<<2, 256, 0, stream>>>(cb, cn);

    for (int n0 = 0; n0 < B; n0 += BC) {
        int bc = (B - n0 < BC) ? (B - n0) : BC;
        const float* xch = x + (size_t)n0 * 2500;

        int t1 = bc * 625;   // conv1: x -> h1 (regB)
        k_conv1<<<(t1 + 255) / 256, 256, 0, stream>>>(xch, ew1, eb1, regB, t1);

        int npix = bc * 169;
        dim3 g2((npix + 255) / 256, 2);  // conv2: regB -> regA (h2)
        k_conv2<<<g2, 256, 0, stream>>>(regB, w2t, eb2, regA, npix);

        // conv3: regA -> regB (z)
        k_conv3<<<(npix + 255) / 256, 256, 0, stream>>>(regA, w3t, eb3, regB, npix);

        // vq: regB (z) -> regA (q), via slice + merge
        dim3 gv((npix + 255) / 256, 2);
        k_vq_slice<<<gv, 256, 0, stream>>>(regB, cb, cn, bestd, bestk, npix);
        k_vq_merge<<<(npix + 255) / 256, 256, 0, stream>>>(regB, cb, bestd, bestk, regA, loss, npix);

        dim3 g4((npix + 255) / 256, 4);  // tconv1: regA (q) -> regB (d1)
        k_tconv1<<<g4, 256, 0, stream>>>(regA, wt1, db1, regB, npix);

        int nq2 = bc * 625;
        dim3 g5((nq2 + 255) / 256, 2);   // tconv2: regB (d1) -> regA (d2)
        k_tconv2<<<g5, 256, 0, stream>>>(regB, wt2, db2, regA, nq2);

        int t6 = bc * 2500;  // convf: regA -> out
        k_convf<<<(t6 + 255) / 256, 256, 0, stream>>>(regA, dw3, db3, out + (size_t)n0 * 2500, t6);
    }
}